// Round 1
// 106.448 us; speedup vs baseline: 1.2032x; 1.2032x over previous
//
#include <hip/hip_runtime.h>
#include <hip/hip_bf16.h>
#include <stdint.h>

// Fused causal attention head, MI355X (gfx950). Round 7.
// attn: split-K=4 (grid 1024 = 4 blocks/CU co-resident), double-buffered
// K/V LDS with ONE barrier per tile (prefetch overlaps compute), and the
// P C-layout -> A-frag transform done fully in-register via
// v_permlane32/16_swap (no Ps LDS roundtrip, no 8-way conflicted reads).
// LPT map: per-CU 4-block set sums to constant work; batch = u&3 keeps
// XCD<->batch L2 pinning. proj/wprep identical to R5/R6 for attribution.

#define EMBED 384
#define HEAD  64
#define NB    4
#define NT    4096
#define NROWS (NB * NT) // 16384
#define NSPLIT 4

#define SCALE_Q 0.18033688011112042f // 0.125 * log2(e), folded into Q

typedef short bf16x8 __attribute__((ext_vector_type(8)));
typedef float f32x4  __attribute__((ext_vector_type(4)));

__device__ __forceinline__ unsigned short bfround(float f) {
    union { float f; unsigned u; } v; v.f = f;
    return (unsigned short)((v.u + 0x8000u) >> 16);
}
__device__ __forceinline__ unsigned packbf(float lo, float hi) {
    union { float f; unsigned u; } a, b; a.f = lo; b.f = hi;
    return ((a.u + 0x8000u) >> 16) | ((b.u + 0x8000u) & 0xFFFF0000u);
}

// gfx950 lane-group swaps. swap32: A_upper32 <-> B_lower32.
// swap16: A rows 1,3 (16-lane rows) <-> B rows 0,2.
__device__ __forceinline__ void pl_swap32(unsigned& a, unsigned& b) {
    asm("v_permlane32_swap_b32 %0, %1" : "+v"(a), "+v"(b));
}
__device__ __forceinline__ void pl_swap16(unsigned& a, unsigned& b) {
    asm("v_permlane16_swap_b32 %0, %1" : "+v"(a), "+v"(b));
}

// ---------------------------------------------------------------------------
__global__ __launch_bounds__(256)
void wprep_kernel(const float* __restrict__ Wq,
                  const float* __restrict__ Wk,
                  const float* __restrict__ Wv,
                  unsigned short* __restrict__ Wt)
{
    int idx = blockIdx.x * 256 + threadIdx.x;
    int k = idx / 192;
    int n = idx - k * 192;
    int sel = n >> 6, nc = n & 63;
    const float* wp = (sel == 0) ? Wq : ((sel == 1) ? Wk : Wv);
    Wt[n * EMBED + k] = bfround(wp[(size_t)k * HEAD + nc]);
}

// ---------------------------------------------------------------------------
// proj: identical to R5 (kept for attribution).
// ---------------------------------------------------------------------------
__global__ __launch_bounds__(256)
void proj_kernel(const float* __restrict__ x,
                 const unsigned short* __restrict__ Wt,
                 unsigned short* __restrict__ Qo,
                 unsigned short* __restrict__ Ko,
                 unsigned short* __restrict__ Vto)
{
    __shared__ __attribute__((aligned(16))) unsigned short ws[96][200];
    __shared__ __attribute__((aligned(16))) unsigned short xs[64][200];
    unsigned short (*vbuf)[72] = (unsigned short (*)[72])&xs[0][0];

    const int t    = threadIdx.x;
    const int w    = t >> 6;
    const int lane = t & 63;
    const int quad = lane >> 4;
    const int l16  = lane & 15;
    const int half = blockIdx.x & 1;
    const int r0   = (blockIdx.x >> 1) * 64;
    const int colbase = half * 96;

    f32x4 acc[6];
#pragma unroll
    for (int i = 0; i < 6; ++i) acc[i] = (f32x4){0.f, 0.f, 0.f, 0.f};

#pragma unroll
    for (int ph = 0; ph < 2; ++ph) {
        if (ph) __syncthreads();
        const int k0 = ph * 192;
#pragma unroll
        for (int i = 0; i < 9; ++i) {
            int idx = t + i * 256;
            int row = idx / 24, c = idx - row * 24;
            *(uint4*)&ws[row][c * 8] =
                *(const uint4*)(Wt + (size_t)(colbase + row) * EMBED + k0 + c * 8);
        }
#pragma unroll
        for (int i = 0; i < 12; ++i) {
            int idx = t + i * 256;
            int row = idx / 48, c4 = idx - row * 48;
            const float4 v = *(const float4*)(x + (size_t)(r0 + row) * EMBED + k0 + c4 * 4);
            uint2 pw; pw.x = packbf(v.x, v.y); pw.y = packbf(v.z, v.w);
            *(uint2*)&xs[row][c4 * 4] = pw;
        }
        __syncthreads();
#pragma unroll
        for (int step = 0; step < 6; ++step) {
            bf16x8 a = *(const bf16x8*)&xs[w * 16 + l16][step * 32 + quad * 8];
#pragma unroll
            for (int ng = 0; ng < 6; ++ng) {
                bf16x8 b = *(const bf16x8*)&ws[ng * 16 + l16][step * 32 + quad * 8];
                acc[ng] = __builtin_amdgcn_mfma_f32_16x16x32_bf16(a, b, acc[ng], 0, 0, 0);
            }
        }
    }
    __syncthreads();

#pragma unroll
    for (int ng = 0; ng < 6; ++ng) {
        int cg = colbase + ng * 16 + l16;
#pragma unroll
        for (int r = 0; r < 4; ++r) {
            int row = r0 + w * 16 + quad * 4 + r;
            float vv = acc[ng][r];
            if (cg < 64) {
                Qo[(size_t)row * HEAD + cg] = bfround(vv * SCALE_Q);
            } else if (cg < 128) {
                Ko[(size_t)row * HEAD + (cg - 64)] = bfround(vv);
            } else {
                vbuf[cg - 128][w * 16 + quad * 4 + r] = bfround(vv);
            }
        }
    }
    __syncthreads();
    if (half == 1) {
        const int batch = r0 >> 12;
        const int s0 = r0 & (NT - 1);
#pragma unroll
        for (int i = 0; i < 2; ++i) {
            int idx = t + i * 256;
            int d = idx >> 3, c = idx & 7;
            *(uint4*)(Vto + ((size_t)(batch * HEAD + d)) * NT + s0 + c * 8) =
                *(const uint4*)&vbuf[d][c * 8];
        }
    }
}

// ---------------------------------------------------------------------------
// attn: 1024 blocks x 256 thr, split-K=4. u -> (g=u>>4): m = g<32 ? 63-g :
// g-32 (per-CU 4-set {63-a, 47-a, a, 16+a} sums const), sp=(u>>2)&3,
// batch=u&3 (XCD-pinned). Block covers q-rows [m*64, m*64+64), wave w owns
// 16. k-tiles kt = sp, sp+4, ... <= m (diag kt==m lands on sp == m&3).
// Double-buffered K/V tiles, XOR-swizzled 16B chunks, ONE barrier per tile:
//   write LDS[cur]; sync; issue loads(j+1); compute LDS[cur].
// P (C layout, packed bf16) -> A-frags entirely in-register:
//   per 32-s half: swap32(d00,d10), swap32(d01,d11), swap16 x2
//   => f0..f3 = dwords of the A-frag. No Ps LDS, no lgkm roundtrip.
// ---------------------------------------------------------------------------
__global__ __launch_bounds__(256, 4)
void attn_kernel(const unsigned short* __restrict__ Qi,
                 const unsigned short* __restrict__ Ki,
                 const unsigned short* __restrict__ Vti,
                 float* __restrict__ opart,
                 float* __restrict__ lpart)
{
    __shared__ __attribute__((aligned(16))) unsigned short Kt[2][64][64];
    __shared__ __attribute__((aligned(16))) unsigned short Vs[2][64][64];

    const int t    = threadIdx.x;
    const int w    = t >> 6;
    const int lane = t & 63;
    const int quad = lane >> 4;
    const int l16  = lane & 15;

    const int u = blockIdx.x;
    const int g = u >> 4;
    const int m = (g < 32) ? (63 - g) : (g - 32);
    const int sp = (u >> 2) & 3;
    const int batch = u & 3;
    const int ntiles = (m >= sp) ? (((m - sp) >> 2) + 1) : 0;
    const int q0 = m * 64 + w * 16; // this wave's q-row base

    const unsigned short* Kbg = Ki  + (size_t)batch * NT * HEAD;
    const unsigned short* Vbg = Vti + (size_t)batch * HEAD * NT;

    // Q B-frags (one-time; Q carries 0.125*log2e)
    bf16x8 bq0, bq1;
    {
        const unsigned short* qp = Qi + (size_t)(batch * NT + q0 + l16) * HEAD + quad * 8;
        bq0 = *(const bf16x8*)(qp);
        bq1 = *(const bf16x8*)(qp + 32);
    }

    f32x4 o[4];
#pragma unroll
    for (int i = 0; i < 4; ++i) o[i] = (f32x4){0.f, 0.f, 0.f, 0.f};
    float rs = 0.f;

    // staging indices (fixed per thread): 2 chunks each of K and V
    const int srow0 = t >> 3, sc = t & 7;
    const int srow1 = (t + 256) >> 3;
    const int scc0 = sc ^ (srow0 & 7);
    const int scc1 = sc ^ (srow1 & 7);
    const int sw = l16 & 7; // row-swizzle key for frag reads

    uint4 kr0, kr1, vr0, vr1;
    if (ntiles > 0) {
        const int kt = sp;
        kr0 = *(const uint4*)(Kbg + (size_t)(kt * 64 + srow0) * HEAD + sc * 8);
        kr1 = *(const uint4*)(Kbg + (size_t)(kt * 64 + srow1) * HEAD + sc * 8);
        vr0 = *(const uint4*)(Vbg + (size_t)srow0 * NT + kt * 64 + sc * 8);
        vr1 = *(const uint4*)(Vbg + (size_t)srow1 * NT + kt * 64 + sc * 8);
    }

    int cur = 0;
    for (int j = 0; j < ntiles; ++j) {
        const int kt = sp + 4 * j;
        // commit staged regs to LDS[cur]. Safe: cur was last read at j-2,
        // separated from these writes by the barrier inside j-1.
        *(uint4*)&Kt[cur][srow0][scc0 * 8] = kr0;
        *(uint4*)&Kt[cur][srow1][scc1 * 8] = kr1;
        *(uint4*)&Vs[cur][srow0][scc0 * 8] = vr0;
        *(uint4*)&Vs[cur][srow1][scc1 * 8] = vr1;
        __syncthreads(); // tile visible; j-1 reads complete

        // prefetch next tile AFTER the barrier (so the pre-barrier vmcnt(0)
        // drain can't serialize it); latency hides under this tile's compute
        if (j + 1 < ntiles) {
            const int ktn = kt + 4;
            kr0 = *(const uint4*)(Kbg + (size_t)(ktn * 64 + srow0) * HEAD + sc * 8);
            kr1 = *(const uint4*)(Kbg + (size_t)(ktn * 64 + srow1) * HEAD + sc * 8);
            vr0 = *(const uint4*)(Vbg + (size_t)srow0 * NT + ktn * 64 + sc * 8);
            vr1 = *(const uint4*)(Vbg + (size_t)srow1 * NT + ktn * 64 + sc * 8);
        }

        const bool diag = (kt == m);
        uint2 pw[4];
#pragma unroll
        for (int ts = 0; ts < 4; ++ts) {
            bf16x8 ak0 = *(const bf16x8*)&Kt[cur][ts * 16 + l16][(quad ^ sw) * 8];
            bf16x8 ak1 = *(const bf16x8*)&Kt[cur][ts * 16 + l16][((4 + quad) ^ sw) * 8];
            f32x4 z = (f32x4){0.f, 0.f, 0.f, 0.f};
            z = __builtin_amdgcn_mfma_f32_16x16x32_bf16(ak0, bq0, z, 0, 0, 0);
            z = __builtin_amdgcn_mfma_f32_16x16x32_bf16(ak1, bq1, z, 0, 0, 0);
            // z[r] = S^T[s = kt*64+ts*16+quad*4+r][q = q0+l16], exp2 domain
            float p[4];
#pragma unroll
            for (int r = 0; r < 4; ++r) {
                float pv = __builtin_amdgcn_exp2f(z[r]);
                if (diag) {
                    int sg = kt * 64 + ts * 16 + quad * 4 + r;
                    pv = (sg > q0 + l16) ? 0.f : pv;
                }
                p[r] = pv;
            }
            rs += (p[0] + p[1]) + (p[2] + p[3]);
            pw[ts].x = packbf(p[0], p[1]);
            pw[ts].y = packbf(p[2], p[3]);
        }

        // In-register C->A transform. Held (per 32-s half h, ts=2h+a):
        // d[a][c] covers s = 32h + 16a + 4*quad + 2c. Wanted at lane-quad q:
        // f[j] covering s = 32h + 8q + 2j.
        //   swap32(d00,d10)->A,B ; swap32(d01,d11)->C,D
        //   swap16(A,B): A=f0, B=f2 ; swap16(C,D): C=f1, D=f3
        unsigned a0 = pw[0].x, c0 = pw[0].y, b0 = pw[1].x, d0 = pw[1].y;
        pl_swap32(a0, b0); pl_swap32(c0, d0);
        pl_swap16(a0, b0); pl_swap16(c0, d0);
        unsigned a1 = pw[2].x, c1 = pw[2].y, b1 = pw[3].x, d1 = pw[3].y;
        pl_swap32(a1, b1); pl_swap32(c1, d1);
        pl_swap16(a1, b1); pl_swap16(c1, d1);
        union { unsigned u[4]; bf16x8 v; } ua0, ua1;
        ua0.u[0] = a0; ua0.u[1] = c0; ua0.u[2] = b0; ua0.u[3] = d0;
        ua1.u[0] = a1; ua1.u[1] = c1; ua1.u[2] = b1; ua1.u[3] = d1;
        const bf16x8 ap0 = ua0.v; // P[q=l16][s = quad*8 + 0..7]
        const bf16x8 ap1 = ua1.v; // P[q=l16][s = 32 + quad*8 + 0..7]

#pragma unroll
        for (int nd = 0; nd < 4; ++nd) {
            bf16x8 av0 = *(const bf16x8*)&Vs[cur][nd * 16 + l16][(quad ^ sw) * 8];
            bf16x8 av1 = *(const bf16x8*)&Vs[cur][nd * 16 + l16][((4 + quad) ^ sw) * 8];
            o[nd] = __builtin_amdgcn_mfma_f32_16x16x32_bf16(ap0, av0, o[nd], 0, 0, 0);
            o[nd] = __builtin_amdgcn_mfma_f32_16x16x32_bf16(ap1, av1, o[nd], 0, 0, 0);
        }
        cur ^= 1;
    }

    // rs: butterfly across quads -> lane holds sum for q = q0 + l16
    rs += __shfl_xor(rs, 16, 64);
    rs += __shfl_xor(rs, 32, 64);
    if (quad == 0)
        lpart[(size_t)sp * NROWS + batch * NT + q0 + l16] = rs;
    float* ob = opart + (size_t)sp * NROWS * HEAD;
#pragma unroll
    for (int r = 0; r < 4; ++r) {
        size_t off = (size_t)(batch * NT + q0 + quad * 4 + r) * HEAD;
#pragma unroll
        for (int nd = 0; nd < 4; ++nd)
            ob[off + nd * 16 + l16] = o[nd][r];
    }
}

// ---------------------------------------------------------------------------
// combine: out = sum_sp(o_sp) / sum_sp(l_sp), one float4 per thread.
// ---------------------------------------------------------------------------
__global__ __launch_bounds__(256)
void combine_kernel(const float* __restrict__ opart,
                    const float* __restrict__ lpart,
                    float* __restrict__ out)
{
    int gid = blockIdx.x * 256 + threadIdx.x;   // 0 .. NROWS*16-1
    int row = gid >> 4;
    int d4  = (gid & 15) * 4;
    const size_t st = (size_t)NROWS * HEAD;
    const float* p0 = opart + (size_t)row * HEAD + d4;
    f32x4 a = *(const f32x4*)(p0);
    f32x4 b = *(const f32x4*)(p0 + st);
    f32x4 c = *(const f32x4*)(p0 + 2 * st);
    f32x4 d = *(const f32x4*)(p0 + 3 * st);
    float inv = 1.0f / (lpart[row] + lpart[NROWS + row] +
                        lpart[2 * NROWS + row] + lpart[3 * NROWS + row]);
    f32x4 res = (a + b) + (c + d);
    res[0] *= inv; res[1] *= inv; res[2] *= inv; res[3] *= inv;
    *(f32x4*)(out + (size_t)row * HEAD + d4) = res;
}

extern "C" void kernel_launch(void* const* d_in, const int* in_sizes, int n_in,
                              void* d_out, int out_size, void* d_ws, size_t ws_size,
                              hipStream_t stream)
{
    const float* x  = (const float*)d_in[0];
    const float* Wq = (const float*)d_in[1];
    const float* Wk = (const float*)d_in[2];
    const float* Wv = (const float*)d_in[3];
    float* out = (float*)d_out;

    // ws: Q | K | V^T (bf16, 2MB each) | W^T (144KB) | opart (16MB) | lpart (256KB)
    unsigned short* Qw  = (unsigned short*)d_ws;
    unsigned short* Kw  = Qw + (size_t)NROWS * HEAD;
    unsigned short* Vtw = Kw + (size_t)NROWS * HEAD;
    unsigned short* Wtw = Vtw + (size_t)NROWS * HEAD;
    float* opart = (float*)(Wtw + (size_t)192 * EMBED);
    float* lpart = opart + (size_t)NSPLIT * NROWS * HEAD;

    wprep_kernel<<<(192 * EMBED) / 256, 256, 0, stream>>>(Wq, Wk, Wv, Wtw);
    proj_kernel<<<512, 256, 0, stream>>>(x, Wtw, Qw, Kw, Vtw);
    attn_kernel<<<1024, 256, 0, stream>>>(Qw, Kw, Vtw, opart, lpart);
    combine_kernel<<<NROWS * 16 / 256, 256, 0, stream>>>(opart, lpart, out);
}

// Round 3
// 105.801 us; speedup vs baseline: 1.2106x; 1.0061x over previous
//
#include <hip/hip_runtime.h>
#include <hip/hip_bf16.h>
#include <stdint.h>

// Fused causal attention head, MI355X (gfx950). Round 8 (resubmit — R2 bench
// failed with GPUAcquisitionTimeout; source never ran).
// proj redesign: single-pass (x read ONCE from HBM), 256 blocks x 512 thr
// (1 block/CU, 8 waves), 64 rows x 192 cols per block, K in 3 phases of 128,
// double-buffered LDS with one barrier per phase + register prefetch of the
// next phase issued right after the barrier (same schedule as attn R7).
// XOR-chunk-swizzled LDS rows (128 shorts, chunk c ^ (row&15)) make staging
// writes and frag reads conflict-free. wprep/attn/combine identical to R7.

#define EMBED 384
#define HEAD  64
#define NB    4
#define NT    4096
#define NROWS (NB * NT) // 16384
#define NSPLIT 4

#define SCALE_Q 0.18033688011112042f // 0.125 * log2(e), folded into Q

typedef short bf16x8 __attribute__((ext_vector_type(8)));
typedef float f32x4  __attribute__((ext_vector_type(4)));

__device__ __forceinline__ unsigned short bfround(float f) {
    union { float f; unsigned u; } v; v.f = f;
    return (unsigned short)((v.u + 0x8000u) >> 16);
}
__device__ __forceinline__ unsigned packbf(float lo, float hi) {
    union { float f; unsigned u; } a, b; a.f = lo; b.f = hi;
    return ((a.u + 0x8000u) >> 16) | ((b.u + 0x8000u) & 0xFFFF0000u);
}

// gfx950 lane-group swaps. swap32: A_upper32 <-> B_lower32.
// swap16: A rows 1,3 (16-lane rows) <-> B rows 0,2.
__device__ __forceinline__ void pl_swap32(unsigned& a, unsigned& b) {
    asm("v_permlane32_swap_b32 %0, %1" : "+v"(a), "+v"(b));
}
__device__ __forceinline__ void pl_swap16(unsigned& a, unsigned& b) {
    asm("v_permlane16_swap_b32 %0, %1" : "+v"(a), "+v"(b));
}

// ---------------------------------------------------------------------------
__global__ __launch_bounds__(256)
void wprep_kernel(const float* __restrict__ Wq,
                  const float* __restrict__ Wk,
                  const float* __restrict__ Wv,
                  unsigned short* __restrict__ Wt)
{
    int idx = blockIdx.x * 256 + threadIdx.x;
    int k = idx / 192;
    int n = idx - k * 192;
    int sel = n >> 6, nc = n & 63;
    const float* wp = (sel == 0) ? Wq : ((sel == 1) ? Wk : Wv);
    Wt[n * EMBED + k] = bfround(wp[(size_t)k * HEAD + nc]);
}

// ---------------------------------------------------------------------------
// proj v2: block b -> rows [b*64, b*64+64), all 192 output cols.
// 512 threads = 8 waves: wave w -> row group wr=w&3 (16 rows), col group
// wc=w>>2 (96 cols = 6 MFMA col-tiles). 3 k-phases of 128, double-buffered.
// Per phase per thread: 4 float4 of x (packed to bf16) + 6 uint4 of Wt.
// LDS rows are 128 shorts = 16 chunks of 16B; physical chunk = c ^ (row&15)
// => staging writes 2-dw/bank, frag reads 8-dw/bank uniform (conflict-free).
// Schedule: commit regs -> barrier -> prefetch(ph+1) -> compute(cur).
// Buffer cur is rewritten at ph+2, separated by barrier(ph+1) from its
// readers at ph (same proof as attn R7).
// ---------------------------------------------------------------------------
__global__ __launch_bounds__(512)
void proj_kernel(const float* __restrict__ x,
                 const unsigned short* __restrict__ Wt,
                 unsigned short* __restrict__ Qo,
                 unsigned short* __restrict__ Ko,
                 unsigned short* __restrict__ Vto)
{
    __shared__ __attribute__((aligned(16))) unsigned short ws[2][192][128]; // 96KB
    __shared__ __attribute__((aligned(16))) unsigned short xs[2][64][128];  // 32KB
    // vbuf overlays xs[1]: last phase (ph=2) computes on buffer 0, and the
    // post-loop barrier orders all prior reads/writes before vbuf writes.
    unsigned short (*vbuf)[72] = (unsigned short (*)[72])&xs[1][0][0];

    const int t    = threadIdx.x;   // 0..511
    const int lane = t & 63;
    const int w    = t >> 6;        // 0..7
    const int quad = lane >> 4;
    const int l16  = lane & 15;
    const int wr   = w & 3;         // row group (16 rows)
    const int wc   = w >> 2;        // col group (96 cols)
    const int r0   = blockIdx.x * 64;

    // staging coords (fixed per thread)
    const int xr  = t >> 5, xc4 = t & 31;        // x: rows xr+16i, float4 col xc4
    const int xch = xc4 >> 1, xsub = (xc4 & 1) * 4;
    const int wrw = t >> 4, wcc = t & 15;        // W: rows wrw+32i, chunk wcc

    f32x4 acc[6];
#pragma unroll
    for (int i = 0; i < 6; ++i) acc[i] = (f32x4){0.f, 0.f, 0.f, 0.f};

    float4 xv[4];
    uint4  wv[6];
    // prologue loads (k0 = 0)
#pragma unroll
    for (int i = 0; i < 4; ++i)
        xv[i] = *(const float4*)(x + (size_t)(r0 + xr + 16 * i) * EMBED + xc4 * 4);
#pragma unroll
    for (int i = 0; i < 6; ++i)
        wv[i] = *(const uint4*)(Wt + (size_t)(wrw + 32 * i) * EMBED + wcc * 8);

    int cur = 0;
#pragma unroll
    for (int ph = 0; ph < 3; ++ph) {
        // commit staged regs to LDS[cur]
#pragma unroll
        for (int i = 0; i < 4; ++i) {
            int row = xr + 16 * i;
            uint2 pw; pw.x = packbf(xv[i].x, xv[i].y); pw.y = packbf(xv[i].z, xv[i].w);
            *(uint2*)&xs[cur][row][((xch ^ (row & 15)) << 3) + xsub] = pw;
        }
#pragma unroll
        for (int i = 0; i < 6; ++i) {
            int row = wrw + 32 * i;
            *(uint4*)&ws[cur][row][(wcc ^ (row & 15)) << 3] = wv[i];
        }
        __syncthreads();

        // prefetch next phase AFTER the barrier; latency hides under compute
        if (ph < 2) {
            const int k0 = (ph + 1) * 128;
#pragma unroll
            for (int i = 0; i < 4; ++i)
                xv[i] = *(const float4*)(x + (size_t)(r0 + xr + 16 * i) * EMBED + k0 + xc4 * 4);
#pragma unroll
            for (int i = 0; i < 6; ++i)
                wv[i] = *(const uint4*)(Wt + (size_t)(wrw + 32 * i) * EMBED + k0 + wcc * 8);
        }

        // compute: 4 k-steps x 6 col-tiles
#pragma unroll
        for (int s = 0; s < 4; ++s) {
            bf16x8 a = *(const bf16x8*)&xs[cur][wr * 16 + l16][((s * 4 + quad) ^ l16) << 3];
#pragma unroll
            for (int ng = 0; ng < 6; ++ng) {
                bf16x8 b = *(const bf16x8*)&ws[cur][wc * 96 + ng * 16 + l16][((s * 4 + quad) ^ l16) << 3];
                acc[ng] = __builtin_amdgcn_mfma_f32_16x16x32_bf16(a, b, acc[ng], 0, 0, 0);
            }
        }
        cur ^= 1;
    }
    __syncthreads(); // all compute done before vbuf overlays xs[1]

#pragma unroll
    for (int ng = 0; ng < 6; ++ng) {
        int cg = wc * 96 + ng * 16 + l16;
#pragma unroll
        for (int r = 0; r < 4; ++r) {
            int row = r0 + wr * 16 + quad * 4 + r;
            float vv = acc[ng][r];
            if (cg < 64) {
                Qo[(size_t)row * HEAD + cg] = bfround(vv * SCALE_Q);
            } else if (cg < 128) {
                Ko[(size_t)row * HEAD + (cg - 64)] = bfround(vv);
            } else {
                vbuf[cg - 128][wr * 16 + quad * 4 + r] = bfround(vv);
            }
        }
    }
    __syncthreads();
    {
        const int batch = r0 >> 12;
        const int s0 = r0 & (NT - 1);
        const int d = t >> 3, c = t & 7;
        *(uint4*)(Vto + ((size_t)(batch * HEAD + d)) * NT + s0 + c * 8) =
            *(const uint4*)&vbuf[d][c * 8];
    }
}

// ---------------------------------------------------------------------------
// attn: identical to R7. 1024 blocks x 256 thr, split-K=4, double-buffered
// K/V LDS, one barrier per tile, in-register P C->A via permlane swaps.
// ---------------------------------------------------------------------------
__global__ __launch_bounds__(256, 4)
void attn_kernel(const unsigned short* __restrict__ Qi,
                 const unsigned short* __restrict__ Ki,
                 const unsigned short* __restrict__ Vti,
                 float* __restrict__ opart,
                 float* __restrict__ lpart)
{
    __shared__ __attribute__((aligned(16))) unsigned short Kt[2][64][64];
    __shared__ __attribute__((aligned(16))) unsigned short Vs[2][64][64];

    const int t    = threadIdx.x;
    const int w    = t >> 6;
    const int lane = t & 63;
    const int quad = lane >> 4;
    const int l16  = lane & 15;

    const int u = blockIdx.x;
    const int g = u >> 4;
    const int m = (g < 32) ? (63 - g) : (g - 32);
    const int sp = (u >> 2) & 3;
    const int batch = u & 3;
    const int ntiles = (m >= sp) ? (((m - sp) >> 2) + 1) : 0;
    const int q0 = m * 64 + w * 16; // this wave's q-row base

    const unsigned short* Kbg = Ki  + (size_t)batch * NT * HEAD;
    const unsigned short* Vbg = Vti + (size_t)batch * HEAD * NT;

    // Q B-frags (one-time; Q carries 0.125*log2e)
    bf16x8 bq0, bq1;
    {
        const unsigned short* qp = Qi + (size_t)(batch * NT + q0 + l16) * HEAD + quad * 8;
        bq0 = *(const bf16x8*)(qp);
        bq1 = *(const bf16x8*)(qp + 32);
    }

    f32x4 o[4];
#pragma unroll
    for (int i = 0; i < 4; ++i) o[i] = (f32x4){0.f, 0.f, 0.f, 0.f};
    float rs = 0.f;

    // staging indices (fixed per thread): 2 chunks each of K and V
    const int srow0 = t >> 3, sc = t & 7;
    const int srow1 = (t + 256) >> 3;
    const int scc0 = sc ^ (srow0 & 7);
    const int scc1 = sc ^ (srow1 & 7);
    const int sw = l16 & 7; // row-swizzle key for frag reads

    uint4 kr0, kr1, vr0, vr1;
    if (ntiles > 0) {
        const int kt = sp;
        kr0 = *(const uint4*)(Kbg + (size_t)(kt * 64 + srow0) * HEAD + sc * 8);
        kr1 = *(const uint4*)(Kbg + (size_t)(kt * 64 + srow1) * HEAD + sc * 8);
        vr0 = *(const uint4*)(Vbg + (size_t)srow0 * NT + kt * 64 + sc * 8);
        vr1 = *(const uint4*)(Vbg + (size_t)srow1 * NT + kt * 64 + sc * 8);
    }

    int cur = 0;
    for (int j = 0; j < ntiles; ++j) {
        const int kt = sp + 4 * j;
        *(uint4*)&Kt[cur][srow0][scc0 * 8] = kr0;
        *(uint4*)&Kt[cur][srow1][scc1 * 8] = kr1;
        *(uint4*)&Vs[cur][srow0][scc0 * 8] = vr0;
        *(uint4*)&Vs[cur][srow1][scc1 * 8] = vr1;
        __syncthreads(); // tile visible; j-1 reads complete

        if (j + 1 < ntiles) {
            const int ktn = kt + 4;
            kr0 = *(const uint4*)(Kbg + (size_t)(ktn * 64 + srow0) * HEAD + sc * 8);
            kr1 = *(const uint4*)(Kbg + (size_t)(ktn * 64 + srow1) * HEAD + sc * 8);
            vr0 = *(const uint4*)(Vbg + (size_t)srow0 * NT + ktn * 64 + sc * 8);
            vr1 = *(const uint4*)(Vbg + (size_t)srow1 * NT + ktn * 64 + sc * 8);
        }

        const bool diag = (kt == m);
        uint2 pw[4];
#pragma unroll
        for (int ts = 0; ts < 4; ++ts) {
            bf16x8 ak0 = *(const bf16x8*)&Kt[cur][ts * 16 + l16][(quad ^ sw) * 8];
            bf16x8 ak1 = *(const bf16x8*)&Kt[cur][ts * 16 + l16][((4 + quad) ^ sw) * 8];
            f32x4 z = (f32x4){0.f, 0.f, 0.f, 0.f};
            z = __builtin_amdgcn_mfma_f32_16x16x32_bf16(ak0, bq0, z, 0, 0, 0);
            z = __builtin_amdgcn_mfma_f32_16x16x32_bf16(ak1, bq1, z, 0, 0, 0);
            float p[4];
#pragma unroll
            for (int r = 0; r < 4; ++r) {
                float pv = __builtin_amdgcn_exp2f(z[r]);
                if (diag) {
                    int sg = kt * 64 + ts * 16 + quad * 4 + r;
                    pv = (sg > q0 + l16) ? 0.f : pv;
                }
                p[r] = pv;
            }
            rs += (p[0] + p[1]) + (p[2] + p[3]);
            pw[ts].x = packbf(p[0], p[1]);
            pw[ts].y = packbf(p[2], p[3]);
        }

        unsigned a0 = pw[0].x, c0 = pw[0].y, b0 = pw[1].x, d0 = pw[1].y;
        pl_swap32(a0, b0); pl_swap32(c0, d0);
        pl_swap16(a0, b0); pl_swap16(c0, d0);
        unsigned a1 = pw[2].x, c1 = pw[2].y, b1 = pw[3].x, d1 = pw[3].y;
        pl_swap32(a1, b1); pl_swap32(c1, d1);
        pl_swap16(a1, b1); pl_swap16(c1, d1);
        union { unsigned u[4]; bf16x8 v; } ua0, ua1;
        ua0.u[0] = a0; ua0.u[1] = c0; ua0.u[2] = b0; ua0.u[3] = d0;
        ua1.u[0] = a1; ua1.u[1] = c1; ua1.u[2] = b1; ua1.u[3] = d1;
        const bf16x8 ap0 = ua0.v;
        const bf16x8 ap1 = ua1.v;

#pragma unroll
        for (int nd = 0; nd < 4; ++nd) {
            bf16x8 av0 = *(const bf16x8*)&Vs[cur][nd * 16 + l16][(quad ^ sw) * 8];
            bf16x8 av1 = *(const bf16x8*)&Vs[cur][nd * 16 + l16][((4 + quad) ^ sw) * 8];
            o[nd] = __builtin_amdgcn_mfma_f32_16x16x32_bf16(ap0, av0, o[nd], 0, 0, 0);
            o[nd] = __builtin_amdgcn_mfma_f32_16x16x32_bf16(ap1, av1, o[nd], 0, 0, 0);
        }
        cur ^= 1;
    }

    rs += __shfl_xor(rs, 16, 64);
    rs += __shfl_xor(rs, 32, 64);
    if (quad == 0)
        lpart[(size_t)sp * NROWS + batch * NT + q0 + l16] = rs;
    float* ob = opart + (size_t)sp * NROWS * HEAD;
#pragma unroll
    for (int r = 0; r < 4; ++r) {
        size_t off = (size_t)(batch * NT + q0 + quad * 4 + r) * HEAD;
#pragma unroll
        for (int nd = 0; nd < 4; ++nd)
            ob[off + nd * 16 + l16] = o[nd][r];
    }
}

// ---------------------------------------------------------------------------
// combine: out = sum_sp(o_sp) / sum_sp(l_sp), one float4 per thread.
// ---------------------------------------------------------------------------
__global__ __launch_bounds__(256)
void combine_kernel(const float* __restrict__ opart,
                    const float* __restrict__ lpart,
                    float* __restrict__ out)
{
    int gid = blockIdx.x * 256 + threadIdx.x;   // 0 .. NROWS*16-1
    int row = gid >> 4;
    int d4  = (gid & 15) * 4;
    const size_t st = (size_t)NROWS * HEAD;
    const float* p0 = opart + (size_t)row * HEAD + d4;
    f32x4 a = *(const f32x4*)(p0);
    f32x4 b = *(const f32x4*)(p0 + st);
    f32x4 c = *(const f32x4*)(p0 + 2 * st);
    f32x4 d = *(const f32x4*)(p0 + 3 * st);
    float inv = 1.0f / (lpart[row] + lpart[NROWS + row] +
                        lpart[2 * NROWS + row] + lpart[3 * NROWS + row]);
    f32x4 res = (a + b) + (c + d);
    res[0] *= inv; res[1] *= inv; res[2] *= inv; res[3] *= inv;
    *(f32x4*)(out + (size_t)row * HEAD + d4) = res;
}

extern "C" void kernel_launch(void* const* d_in, const int* in_sizes, int n_in,
                              void* d_out, int out_size, void* d_ws, size_t ws_size,
                              hipStream_t stream)
{
    const float* x  = (const float*)d_in[0];
    const float* Wq = (const float*)d_in[1];
    const float* Wk = (const float*)d_in[2];
    const float* Wv = (const float*)d_in[3];
    float* out = (float*)d_out;

    // ws: Q | K | V^T (bf16, 2MB each) | W^T (144KB) | opart (16MB) | lpart (256KB)
    unsigned short* Qw  = (unsigned short*)d_ws;
    unsigned short* Kw  = Qw + (size_t)NROWS * HEAD;
    unsigned short* Vtw = Kw + (size_t)NROWS * HEAD;
    unsigned short* Wtw = Vtw + (size_t)NROWS * HEAD;
    float* opart = (float*)(Wtw + (size_t)192 * EMBED);
    float* lpart = opart + (size_t)NSPLIT * NROWS * HEAD;

    wprep_kernel<<<(192 * EMBED) / 256, 256, 0, stream>>>(Wq, Wk, Wv, Wtw);
    proj_kernel<<<256, 512, 0, stream>>>(x, Wtw, Qw, Kw, Vtw);
    attn_kernel<<<1024, 256, 0, stream>>>(Qw, Kw, Vtw, opart, lpart);
    combine_kernel<<<NROWS * 16 / 256, 256, 0, stream>>>(opart, lpart, out);
}